// Round 4
// baseline (451.624 us; speedup 1.0000x reference)
//
#include <hip/hip_runtime.h>

#define NN 50000
#define NE 600000
#define DD 128
#define NG 64

typedef unsigned int uint;
typedef unsigned short ushort;
typedef __attribute__((ext_vector_type(8))) short short8;
typedef __attribute__((ext_vector_type(4))) float f4;

// ---------------- bf16 helpers ----------------

__device__ __forceinline__ float bf_lo(uint v) { return __uint_as_float(v << 16); }
__device__ __forceinline__ float bf_hi(uint v) { return __uint_as_float(v & 0xffff0000u); }
__device__ __forceinline__ float bf2f(ushort h) { return __uint_as_float((uint)h << 16); }
__device__ __forceinline__ ushort f2bf(float f) {
    uint u = __float_as_uint(f);
    uint r = (u + 0x7fffu + ((u >> 16) & 1u)) >> 16;   // round-nearest-even
    return (ushort)r;
}

// ---------------- setup kernels ----------------

__global__ void k_hist(const int* __restrict__ dstv, int* __restrict__ deg) {
    int e = blockIdx.x * 256 + threadIdx.x;
    if (e < NE) atomicAdd(&deg[dstv[e]], 1);
}

// deg holds edge-count only; +1 self-loop folded in here.
__global__ void k_scan1(const int* __restrict__ deg, float* __restrict__ dinv,
                        int* __restrict__ rp, int* __restrict__ bsum) {
    __shared__ int s[256];
    int t = threadIdx.x, i = blockIdx.x * 256 + t;
    int v = (i < NN) ? (deg[i] + 1) : 0;
    if (i < NN) dinv[i] = rsqrtf((float)v);
    s[t] = v; __syncthreads();
    for (int off = 1; off < 256; off <<= 1) {
        int x = (t >= off) ? s[t - off] : 0;
        __syncthreads();
        s[t] += x;
        __syncthreads();
    }
    if (i < NN) rp[i] = s[t] - v;           // exclusive
    if (t == 255) bsum[blockIdx.x] = s[255];
}

__global__ void k_scan2(int* bs, int nb) {
    __shared__ int s[256];
    int t = threadIdx.x;
    int v = (t < nb) ? bs[t] : 0;
    s[t] = v; __syncthreads();
    for (int off = 1; off < 256; off <<= 1) {
        int x = (t >= off) ? s[t - off] : 0;
        __syncthreads();
        s[t] += x;
        __syncthreads();
    }
    if (t < nb) bs[t] = s[t] - v;
}

__global__ void k_scan3(int* rp, const int* bs) {
    int i = blockIdx.x * 256 + threadIdx.x;
    if (i < NN) rp[i] += bs[i >> 8];
    if (i == 0) rp[NN] = NE + NN;
}

__global__ void k_scatter(const int* __restrict__ srcv, const int* __restrict__ dstv,
                          const int* __restrict__ rp, int* __restrict__ fill,
                          int* __restrict__ col) {
    int t = blockIdx.x * 256 + threadIdx.x;
    if (t < NE) {
        int s = srcv[t], d = dstv[t];
        int pos = rp[d] + atomicAdd(&fill[d], 1);
        col[pos] = s;
    } else if (t < NE + NN) {
        int i = t - NE;
        int pos = rp[i] + atomicAdd(&fill[i], 1);
        col[pos] = i;
    }
}

// Pack W [128x128 f32] into MFMA B-fragment layout, split bf16 hi + lo.
// frag g = (nt*4 + kk)*64 + lane; elem j: k = kk*32 + (lane>>4)*8 + j,
// n = nt*16 + (lane&15). out: base[g*8+j] = hi, base[16384 + g*8+j] = lo.
__global__ void k_wpack(const float* __restrict__ W1, const float* __restrict__ W2,
                        const float* __restrict__ W3, short* __restrict__ out) {
    const float* W = (blockIdx.y == 0) ? W1 : (blockIdx.y == 1) ? W2 : W3;
    short* base = out + (size_t)blockIdx.y * 32768;
    int g = blockIdx.x * 256 + threadIdx.x;   // 0..2047
    int nt = g >> 8, kk = (g >> 6) & 3, lane = g & 63;
    int k0 = kk * 32 + (lane >> 4) * 8;
    int n = nt * 16 + (lane & 15);
    #pragma unroll
    for (int j = 0; j < 8; ++j) {
        float w = W[(size_t)(k0 + j) * DD + n];
        ushort h = f2bf(w);
        float r = w - bf2f(h);
        base[g * 8 + j] = (short)h;
        base[16384 + g * 8 + j] = (short)f2bf(r);
    }
}

// ---------------- MFMA GEMM ----------------
// out[r][c] = bf16( (X[r][:] @ W[:][c]) * dinv[r] )
// N split across blockIdx.y (2 halves of 64 cols) -> 32 KB LDS, 782 blocks.
template <int INF32>
__global__ __launch_bounds__(256) void k_gemm_mfma(const void* __restrict__ Xv,
                                                   const short* __restrict__ wpk,
                                                   const float* __restrict__ dinv,
                                                   ushort* __restrict__ out) {
    __shared__ short lds[16384];   // [0,8192) Whi frags, [8192,16384) Wlo (this half)
    const int t = threadIdx.x;
    const int yb = blockIdx.y * 8192;
    #pragma unroll
    for (int m = 0; m < 4; ++m) {
        int idx = (m * 256 + t) * 8;
        *(float4*)&lds[idx] = *(const float4*)&wpk[yb + idx];
        *(float4*)&lds[8192 + idx] = *(const float4*)&wpk[16384 + yb + idx];
    }

    const int wv = t >> 6, lane = t & 63;
    const int quad = lane >> 4, l16 = lane & 15;
    const int r0 = blockIdx.x * 128 + wv * 32;

    short8 aH[2][4], aL[2][4];
    #pragma unroll
    for (int s = 0; s < 2; ++s) {
        int row = r0 + s * 16 + l16;
        #pragma unroll
        for (int kk = 0; kk < 4; ++kk) {
            int koff = kk * 32 + quad * 8;
            if (INF32) {
                float4 x0 = make_float4(0.f, 0.f, 0.f, 0.f), x1 = x0;
                if (row < NN) {
                    const float* p = (const float*)Xv + (size_t)row * DD + koff;
                    x0 = *(const float4*)p; x1 = *(const float4*)(p + 4);
                }
                float xs[8] = {x0.x, x0.y, x0.z, x0.w, x1.x, x1.y, x1.z, x1.w};
                short8 h, l;
                #pragma unroll
                for (int j = 0; j < 8; ++j) {
                    ushort hb = f2bf(xs[j]);
                    h[j] = (short)hb;
                    l[j] = (short)f2bf(xs[j] - bf2f(hb));
                }
                aH[s][kk] = h; aL[s][kk] = l;
            } else {
                short8 h = {0, 0, 0, 0, 0, 0, 0, 0};
                if (row < NN)
                    h = *(const short8*)((const ushort*)Xv + (size_t)row * DD + koff);
                aH[s][kk] = h;
            }
        }
    }
    __syncthreads();

    float dv[2][4];
    #pragma unroll
    for (int s = 0; s < 2; ++s)
        #pragma unroll
        for (int i = 0; i < 4; ++i) {
            int row = r0 + s * 16 + quad * 4 + i;
            dv[s][i] = (row < NN) ? dinv[row] : 0.f;
        }

    #pragma unroll
    for (int nt = 0; nt < 4; ++nt) {
        f4 acc0 = {0.f, 0.f, 0.f, 0.f}, acc1 = acc0;
        #pragma unroll
        for (int kk = 0; kk < 4; ++kk) {
            int fi = ((nt * 4 + kk) * 64 + lane) * 8;
            short8 bh = *(const short8*)&lds[fi];
            short8 bl = *(const short8*)&lds[8192 + fi];
            acc0 = __builtin_amdgcn_mfma_f32_16x16x32_bf16(aH[0][kk], bh, acc0, 0, 0, 0);
            acc0 = __builtin_amdgcn_mfma_f32_16x16x32_bf16(aH[0][kk], bl, acc0, 0, 0, 0);
            acc1 = __builtin_amdgcn_mfma_f32_16x16x32_bf16(aH[1][kk], bh, acc1, 0, 0, 0);
            acc1 = __builtin_amdgcn_mfma_f32_16x16x32_bf16(aH[1][kk], bl, acc1, 0, 0, 0);
            if (INF32) {
                acc0 = __builtin_amdgcn_mfma_f32_16x16x32_bf16(aL[0][kk], bh, acc0, 0, 0, 0);
                acc1 = __builtin_amdgcn_mfma_f32_16x16x32_bf16(aL[1][kk], bh, acc1, 0, 0, 0);
            }
        }
        int cb = (blockIdx.y * 4 + nt) * 16 + l16;
        #pragma unroll
        for (int i = 0; i < 4; ++i) {
            int row0w = r0 + quad * 4 + i;
            if (row0w < NN)
                out[(size_t)row0w * DD + cb] = f2bf(acc0[i] * dv[0][i]);
            int row1w = r0 + 16 + quad * 4 + i;
            if (row1w < NN)
                out[(size_t)row1w * DD + cb] = f2bf(acc1[i] * dv[1][i]);
        }
    }
}

// ---------------- sliced aggregation ----------------
// Slice s = blockIdx.y covers dims [s*32, s*32+32): 3.2 MB table slice fits
// per-XCD L2. Wave = 1 node; lane = e4*16 + dl: 4 edges in flight x 16 lanes
// (2 dims each). Cross-reduce over e4 groups via shfl_xor(16|32).
template <int RELU, int OUTF32>
__global__ __launch_bounds__(256) void k_agg(const ushort* __restrict__ hs,
                                             const int* __restrict__ col,
                                             const int* __restrict__ rp,
                                             const float* __restrict__ dinv,
                                             const float* __restrict__ bias,
                                             void* __restrict__ outv) {
    const int wv = threadIdx.x >> 6, lane = threadIdx.x & 63;
    const int e4 = lane >> 4, dl = lane & 15;
    const int i = blockIdx.x * 4 + wv;
    if (i >= NN) return;
    const int d = blockIdx.y * 32 + dl * 2;
    const int p1 = rp[i + 1];
    int p = rp[i] + e4;
    float a0 = 0.f, a1 = 0.f, b0 = 0.f, b1 = 0.f;
    for (; p + 4 < p1; p += 8) {
        int c0 = col[p], c1 = col[p + 4];
        uint v0 = *(const uint*)(hs + (size_t)c0 * DD + d);
        uint v1 = *(const uint*)(hs + (size_t)c1 * DD + d);
        a0 += bf_lo(v0); a1 += bf_hi(v0);
        b0 += bf_lo(v1); b1 += bf_hi(v1);
    }
    if (p < p1) {
        uint v = *(const uint*)(hs + (size_t)col[p] * DD + d);
        a0 += bf_lo(v); a1 += bf_hi(v);
    }
    a0 += b0; a1 += b1;
    a0 += __shfl_xor(a0, 16); a0 += __shfl_xor(a0, 32);
    a1 += __shfl_xor(a1, 16); a1 += __shfl_xor(a1, 32);
    if (lane < 16) {
        float sc = dinv[i];
        float2 bb = *(const float2*)(bias + d);
        float ox = fmaf(sc, a0, bb.x), oy = fmaf(sc, a1, bb.y);
        if (RELU) { ox = fmaxf(ox, 0.f); oy = fmaxf(oy, 0.f); }
        if (OUTF32) {
            *(float2*)((float*)outv + (size_t)i * DD + d) = make_float2(ox, oy);
        } else {
            ushort2 o; o.x = f2bf(ox); o.y = f2bf(oy);
            *(ushort2*)((ushort*)outv + (size_t)i * DD + d) = o;
        }
    }
}

// batch sorted: run-length accumulate per 128-node chunk
__global__ void k_pool(const float* __restrict__ h, const int* __restrict__ batch,
                       float* __restrict__ sums, float* __restrict__ cnt) {
    int d = threadIdx.x;  // 0..127
    int start = blockIdx.x * 128;
    if (start >= NN) return;
    int end = min(start + 128, NN);
    float acc = 0.f, c = 0.f;
    int g = batch[start];
    for (int i = start; i < end; ++i) {
        int gi = batch[i];
        if (gi != g) {
            atomicAdd(&sums[g * DD + d], acc);
            if (d == 0) atomicAdd(&cnt[g], c);
            acc = 0.f; c = 0.f; g = gi;
        }
        acc += h[(size_t)i * DD + d];
        c += 1.f;
    }
    atomicAdd(&sums[g * DD + d], acc);
    if (d == 0) atomicAdd(&cnt[g], c);
}

__global__ void k_final(const float* __restrict__ sums, const float* __restrict__ cnt,
                        float* __restrict__ out) {
    int i = blockIdx.x * 256 + threadIdx.x;  // < NG*DD = 8192
    int g = i >> 7;
    out[i] = sums[i] / fmaxf(cnt[g], 1.f);
}

// ---------------- launch ----------------

extern "C" void kernel_launch(void* const* d_in, const int* in_sizes, int n_in,
                              void* d_out, int out_size, void* d_ws, size_t ws_size,
                              hipStream_t stream) {
    (void)in_sizes; (void)n_in; (void)out_size; (void)ws_size;
    const float* x  = (const float*)d_in[0];
    const int*   ei = (const int*)d_in[1];
    const int*   bt = (const int*)d_in[2];
    const float* W1 = (const float*)d_in[3];
    const float* b1 = (const float*)d_in[4];
    const float* W2 = (const float*)d_in[5];
    const float* b2 = (const float*)d_in[6];
    const float* W3 = (const float*)d_in[7];
    const float* b3 = (const float*)d_in[8];
    float* out = (float*)d_out;
    char* ws = (char*)d_ws;

    size_t o = 0;
    auto alloc = [&](size_t bytes) { size_t r = o; o = (o + bytes + 511) & ~(size_t)511; return r; };
    // zero-init region first (deg, fill, pool contiguous -> one memset)
    int*    deg  = (int*)(ws + alloc((size_t)NN * 4));
    int*    fill = (int*)(ws + alloc((size_t)NN * 4));
    float*  pool = (float*)(ws + alloc((size_t)(NG * DD + NG) * 4));
    float*  cnt  = pool + NG * DD;
    size_t zbytes = o;
    float*  dinv = (float*)(ws + alloc((size_t)NN * 4));
    int*    rp   = (int*)(ws + alloc((size_t)(NN + 1) * 4));
    int*    bs   = (int*)(ws + alloc(256 * 4));
    int*    col  = (int*)(ws + alloc((size_t)(NE + NN) * 4));
    short*  wpk  = (short*)(ws + alloc((size_t)3 * 32768 * 2));
    ushort* hsT  = (ushort*)(ws + alloc((size_t)NN * DD * 2));
    ushort* hsA  = (ushort*)(ws + alloc((size_t)NN * DD * 2));
    float*  F    = (float*)(ws + alloc((size_t)NN * DD * 4));

    const int* srcv = ei;        // edge_index[0]
    const int* dstv = ei + NE;   // edge_index[1]

    hipMemsetAsync(ws, 0, zbytes, stream);

    k_hist<<<(NE + 255) / 256, 256, 0, stream>>>(dstv, deg);
    k_scan1<<<196, 256, 0, stream>>>(deg, dinv, rp, bs);
    k_scan2<<<1, 256, 0, stream>>>(bs, 196);
    k_scan3<<<196, 256, 0, stream>>>(rp, bs);
    k_scatter<<<(NE + NN + 255) / 256, 256, 0, stream>>>(srcv, dstv, rp, fill, col);
    k_wpack<<<dim3(8, 3), 256, 0, stream>>>(W1, W2, W3, wpk);

    const dim3 gG((NN + 127) / 128, 2);   // 391 x 2
    const dim3 gA(12500, 4);              // nodes/4 x slices
    k_gemm_mfma<1><<<gG, 256, 0, stream>>>(x, wpk, dinv, hsT);
    k_agg<1, 0><<<gA, 256, 0, stream>>>(hsT, col, rp, dinv, b1, hsA);
    k_gemm_mfma<0><<<gG, 256, 0, stream>>>(hsA, wpk + 32768, dinv, hsT);
    k_agg<1, 0><<<gA, 256, 0, stream>>>(hsT, col, rp, dinv, b2, hsA);
    k_gemm_mfma<0><<<gG, 256, 0, stream>>>(hsA, wpk + 65536, dinv, hsT);
    k_agg<0, 1><<<gA, 256, 0, stream>>>(hsT, col, rp, dinv, b3, F);

    k_pool<<<(NN + 127) / 128, 128, 0, stream>>>(F, bt, pool, cnt);
    k_final<<<(NG * DD) / 256, 256, 0, stream>>>(pool, cnt, out);
}

// Round 5
// 349.512 us; speedup vs baseline: 1.2922x; 1.2922x over previous
//
#include <hip/hip_runtime.h>

#define NN 50000
#define NE 600000
#define DD 128
#define NG 64

typedef unsigned int uint;
typedef unsigned short ushort;
typedef __attribute__((ext_vector_type(8))) short short8;
typedef __attribute__((ext_vector_type(4))) float f4;

// ---------------- bf16 helpers ----------------

__device__ __forceinline__ float bf_lo(uint v) { return __uint_as_float(v << 16); }
__device__ __forceinline__ float bf_hi(uint v) { return __uint_as_float(v & 0xffff0000u); }
__device__ __forceinline__ float bf2f(ushort h) { return __uint_as_float((uint)h << 16); }
__device__ __forceinline__ ushort f2bf(float f) {
    uint u = __float_as_uint(f);
    uint r = (u + 0x7fffu + ((u >> 16) & 1u)) >> 16;   // round-nearest-even
    return (ushort)r;
}

// ---------------- setup kernels ----------------

__global__ void k_hist(const int* __restrict__ dstv, int* __restrict__ deg) {
    int e = blockIdx.x * 256 + threadIdx.x;
    if (e < NE) atomicAdd(&deg[dstv[e]], 1);
}

// deg holds edge-count only; +1 self-loop folded in here.
__global__ void k_scan1(const int* __restrict__ deg, float* __restrict__ dinv,
                        int* __restrict__ rp, int* __restrict__ bsum) {
    __shared__ int s[256];
    int t = threadIdx.x, i = blockIdx.x * 256 + t;
    int v = (i < NN) ? (deg[i] + 1) : 0;
    if (i < NN) dinv[i] = rsqrtf((float)v);
    s[t] = v; __syncthreads();
    for (int off = 1; off < 256; off <<= 1) {
        int x = (t >= off) ? s[t - off] : 0;
        __syncthreads();
        s[t] += x;
        __syncthreads();
    }
    if (i < NN) rp[i] = s[t] - v;           // exclusive
    if (t == 255) bsum[blockIdx.x] = s[255];
}

// fused scan2+scan3: every block scans the 196 block-sums itself (cheap),
// then adds its prefix to rp.
__global__ void k_scan23(int* __restrict__ rp, const int* __restrict__ bs) {
    __shared__ int s[256];
    int t = threadIdx.x;
    int v = (t < 196) ? bs[t] : 0;
    s[t] = v; __syncthreads();
    for (int off = 1; off < 256; off <<= 1) {
        int x = (t >= off) ? s[t - off] : 0;
        __syncthreads();
        s[t] += x;
        __syncthreads();
    }
    __shared__ int ps[256];
    ps[t] = s[t] - v;                        // exclusive
    __syncthreads();
    int add = ps[blockIdx.x];
    int i = blockIdx.x * 256 + t;
    if (i < NN) rp[i] += add;
    if (i == 0) rp[NN] = NE + NN;
}

__global__ void k_scatter(const int* __restrict__ srcv, const int* __restrict__ dstv,
                          const int* __restrict__ rp, int* __restrict__ fill,
                          int* __restrict__ col) {
    int t = blockIdx.x * 256 + threadIdx.x;
    if (t < NE) {
        int s = srcv[t], d = dstv[t];
        int pos = rp[d] + atomicAdd(&fill[d], 1);
        col[pos] = s;
    } else if (t < NE + NN) {
        int i = t - NE;
        int pos = rp[i] + atomicAdd(&fill[i], 1);
        col[pos] = i;
    }
}

// Pack W [128x128 f32] into MFMA B-fragment layout, split bf16 hi + lo.
// frag g = (nt*4 + kk)*64 + lane; elem j: k = kk*32 + (lane>>4)*8 + j,
// n = nt*16 + (lane&15). out: base[g*8+j] = hi, base[16384 + g*8+j] = lo.
__global__ void k_wpack(const float* __restrict__ W1, const float* __restrict__ W2,
                        const float* __restrict__ W3, short* __restrict__ out) {
    const float* W = (blockIdx.y == 0) ? W1 : (blockIdx.y == 1) ? W2 : W3;
    short* base = out + (size_t)blockIdx.y * 32768;
    int g = blockIdx.x * 256 + threadIdx.x;   // 0..2047
    int nt = g >> 8, kk = (g >> 6) & 3, lane = g & 63;
    int k0 = kk * 32 + (lane >> 4) * 8;
    int n = nt * 16 + (lane & 15);
    #pragma unroll
    for (int j = 0; j < 8; ++j) {
        float w = W[(size_t)(k0 + j) * DD + n];
        ushort h = f2bf(w);
        float r = w - bf2f(h);
        base[g * 8 + j] = (short)h;
        base[16384 + g * 8 + j] = (short)f2bf(r);
    }
}

// ---------------- MFMA GEMM ----------------
// out[r][c] = bf16( (X[r][:] @ W[:][c]) * dinv[r] )
// N split across blockIdx.y (2 halves of 64 cols); 32 KB LDS for W frags,
// reused post-barrier to stage C for coalesced float4 stores.
#define CST 72   // C-stage LDS row stride in shorts (pad: quads land on distinct banks)
template <int INF32>
__global__ __launch_bounds__(256) void k_gemm_mfma(const void* __restrict__ Xv,
                                                   const short* __restrict__ wpk,
                                                   const float* __restrict__ dinv,
                                                   ushort* __restrict__ out) {
    __shared__ short lds[16384];   // W: hi [0,8192), lo [8192,16384); C-stage: [0, 128*CST)
    const int t = threadIdx.x;
    const int yb = blockIdx.y * 8192;
    #pragma unroll
    for (int m = 0; m < 4; ++m) {
        int idx = (m * 256 + t) * 8;
        *(float4*)&lds[idx] = *(const float4*)&wpk[yb + idx];
        *(float4*)&lds[8192 + idx] = *(const float4*)&wpk[16384 + yb + idx];
    }

    const int wv = t >> 6, lane = t & 63;
    const int quad = lane >> 4, l16 = lane & 15;
    const int r0 = blockIdx.x * 128 + wv * 32;

    short8 aH[2][4], aL[2][4];
    #pragma unroll
    for (int s = 0; s < 2; ++s) {
        int row = r0 + s * 16 + l16;
        #pragma unroll
        for (int kk = 0; kk < 4; ++kk) {
            int koff = kk * 32 + quad * 8;
            if (INF32) {
                float4 x0 = make_float4(0.f, 0.f, 0.f, 0.f), x1 = x0;
                if (row < NN) {
                    const float* p = (const float*)Xv + (size_t)row * DD + koff;
                    x0 = *(const float4*)p; x1 = *(const float4*)(p + 4);
                }
                float xs[8] = {x0.x, x0.y, x0.z, x0.w, x1.x, x1.y, x1.z, x1.w};
                short8 h, l;
                #pragma unroll
                for (int j = 0; j < 8; ++j) {
                    ushort hb = f2bf(xs[j]);
                    h[j] = (short)hb;
                    l[j] = (short)f2bf(xs[j] - bf2f(hb));
                }
                aH[s][kk] = h; aL[s][kk] = l;
            } else {
                short8 h = {0, 0, 0, 0, 0, 0, 0, 0};
                if (row < NN)
                    h = *(const short8*)((const ushort*)Xv + (size_t)row * DD + koff);
                aH[s][kk] = h;
            }
        }
    }
    __syncthreads();

    float dv[2][4];
    #pragma unroll
    for (int s = 0; s < 2; ++s)
        #pragma unroll
        for (int i = 0; i < 4; ++i) {
            int row = r0 + s * 16 + quad * 4 + i;
            dv[s][i] = (row < NN) ? dinv[row] : 0.f;
        }

    f4 acc[2][4];
    #pragma unroll
    for (int s = 0; s < 2; ++s)
        #pragma unroll
        for (int nt = 0; nt < 4; ++nt)
            acc[s][nt] = (f4){0.f, 0.f, 0.f, 0.f};

    #pragma unroll
    for (int nt = 0; nt < 4; ++nt) {
        #pragma unroll
        for (int kk = 0; kk < 4; ++kk) {
            int fi = ((nt * 4 + kk) * 64 + lane) * 8;
            short8 bh = *(const short8*)&lds[fi];
            short8 bl = *(const short8*)&lds[8192 + fi];
            acc[0][nt] = __builtin_amdgcn_mfma_f32_16x16x32_bf16(aH[0][kk], bh, acc[0][nt], 0, 0, 0);
            acc[0][nt] = __builtin_amdgcn_mfma_f32_16x16x32_bf16(aH[0][kk], bl, acc[0][nt], 0, 0, 0);
            acc[1][nt] = __builtin_amdgcn_mfma_f32_16x16x32_bf16(aH[1][kk], bh, acc[1][nt], 0, 0, 0);
            acc[1][nt] = __builtin_amdgcn_mfma_f32_16x16x32_bf16(aH[1][kk], bl, acc[1][nt], 0, 0, 0);
            if (INF32) {
                acc[0][nt] = __builtin_amdgcn_mfma_f32_16x16x32_bf16(aL[0][kk], bh, acc[0][nt], 0, 0, 0);
                acc[1][nt] = __builtin_amdgcn_mfma_f32_16x16x32_bf16(aL[1][kk], bh, acc[1][nt], 0, 0, 0);
            }
        }
    }

    __syncthreads();   // all waves done reading W frags -> reuse LDS for C stage
    #pragma unroll
    for (int s = 0; s < 2; ++s) {
        int lr = wv * 32 + s * 16 + quad * 4;
        #pragma unroll
        for (int nt = 0; nt < 4; ++nt)
            #pragma unroll
            for (int i = 0; i < 4; ++i)
                lds[(lr + i) * CST + nt * 16 + l16] = (short)f2bf(acc[s][nt][i] * dv[s][i]);
    }
    __syncthreads();

    // coalesced writeback: thread t -> row t>>1, half-row (t&1)*32 shorts
    int row = t >> 1, half = t & 1;
    int grow = blockIdx.x * 128 + row;
    if (grow < NN) {
        #pragma unroll
        for (int j = 0; j < 4; ++j) {
            float4 v = *(float4*)&lds[row * CST + half * 32 + j * 8];
            *(float4*)&out[(size_t)grow * DD + blockIdx.y * 64 + half * 32 + j * 8] = v;
        }
    }
}

// ---------------- aggregation ----------------
// out[i] = maybe_relu( dinv[i] * sum_{p in row i} hs[col[p]] + bias )
// Wave per node, lane = 1 dword (2 dims) of the 256B row; 8 rows in flight.
template <int RELU, int OUTF32>
__global__ __launch_bounds__(256) void k_agg(const ushort* __restrict__ hs,
                                             const int* __restrict__ col,
                                             const int* __restrict__ rp,
                                             const float* __restrict__ dinv,
                                             const float* __restrict__ bias,
                                             void* __restrict__ outv) {
    int w = threadIdx.x >> 6, lane = threadIdx.x & 63;
    int i = blockIdx.x * 4 + w;
    if (i >= NN) return;
    int p0 = rp[i], p1 = rp[i + 1];
    int d = lane * 2;
    const ushort* hsd = hs + d;
    float x0 = 0.f, y0 = 0.f, x1 = 0.f, y1 = 0.f;
    float x2 = 0.f, y2 = 0.f, x3 = 0.f, y3 = 0.f;
    int p = p0;
    for (; p + 8 <= p1; p += 8) {
        int c0 = col[p],     c1 = col[p + 1], c2 = col[p + 2], c3 = col[p + 3];
        int c4 = col[p + 4], c5 = col[p + 5], c6 = col[p + 6], c7 = col[p + 7];
        uint v0 = *(const uint*)(hsd + (size_t)c0 * DD);
        uint v1 = *(const uint*)(hsd + (size_t)c1 * DD);
        uint v2 = *(const uint*)(hsd + (size_t)c2 * DD);
        uint v3 = *(const uint*)(hsd + (size_t)c3 * DD);
        uint v4 = *(const uint*)(hsd + (size_t)c4 * DD);
        uint v5 = *(const uint*)(hsd + (size_t)c5 * DD);
        uint v6 = *(const uint*)(hsd + (size_t)c6 * DD);
        uint v7 = *(const uint*)(hsd + (size_t)c7 * DD);
        x0 += bf_lo(v0); y0 += bf_hi(v0); x1 += bf_lo(v1); y1 += bf_hi(v1);
        x2 += bf_lo(v2); y2 += bf_hi(v2); x3 += bf_lo(v3); y3 += bf_hi(v3);
        x0 += bf_lo(v4); y0 += bf_hi(v4); x1 += bf_lo(v5); y1 += bf_hi(v5);
        x2 += bf_lo(v6); y2 += bf_hi(v6); x3 += bf_lo(v7); y3 += bf_hi(v7);
    }
    for (; p + 2 <= p1; p += 2) {
        int c0 = col[p], c1 = col[p + 1];
        uint v0 = *(const uint*)(hsd + (size_t)c0 * DD);
        uint v1 = *(const uint*)(hsd + (size_t)c1 * DD);
        x0 += bf_lo(v0); y0 += bf_hi(v0); x1 += bf_lo(v1); y1 += bf_hi(v1);
    }
    if (p < p1) {
        uint v = *(const uint*)(hsd + (size_t)col[p] * DD);
        x0 += bf_lo(v); y0 += bf_hi(v);
    }
    float ax = (x0 + x1) + (x2 + x3);
    float ay = (y0 + y1) + (y2 + y3);
    float s = dinv[i];
    float2 bb = *(const float2*)(bias + d);
    float ox = fmaf(s, ax, bb.x), oy = fmaf(s, ay, bb.y);
    if (RELU) { ox = fmaxf(ox, 0.f); oy = fmaxf(oy, 0.f); }
    if (OUTF32) {
        *(float2*)((float*)outv + (size_t)i * DD + d) = make_float2(ox, oy);
    } else {
        ushort2 o; o.x = f2bf(ox); o.y = f2bf(oy);
        *(ushort2*)((ushort*)outv + (size_t)i * DD + d) = o;
    }
}

// ---------------- pool (fused mean, no atomics) ----------------
// batch sorted: block g binary-searches its node range, 128 threads = dims.
__global__ __launch_bounds__(128) void k_poolfinal(const float* __restrict__ h,
                                                   const int* __restrict__ batch,
                                                   float* __restrict__ out) {
    int g = blockIdx.x, d = threadIdx.x;
    int lo = 0, hi = NN;
    while (lo < hi) { int m = (lo + hi) >> 1; if (batch[m] < g) lo = m + 1; else hi = m; }
    int s0 = lo;
    hi = NN;
    while (lo < hi) { int m = (lo + hi) >> 1; if (batch[m] < g + 1) lo = m + 1; else hi = m; }
    int s1 = lo;
    float a0 = 0.f, a1 = 0.f, a2 = 0.f, a3 = 0.f;
    int i = s0;
    for (; i + 4 <= s1; i += 4) {
        a0 += h[(size_t)i * DD + d];
        a1 += h[(size_t)(i + 1) * DD + d];
        a2 += h[(size_t)(i + 2) * DD + d];
        a3 += h[(size_t)(i + 3) * DD + d];
    }
    for (; i < s1; ++i) a0 += h[(size_t)i * DD + d];
    float acc = (a0 + a1) + (a2 + a3);
    float c = (float)(s1 - s0);
    out[g * DD + d] = acc / fmaxf(c, 1.f);
}

// ---------------- launch ----------------

extern "C" void kernel_launch(void* const* d_in, const int* in_sizes, int n_in,
                              void* d_out, int out_size, void* d_ws, size_t ws_size,
                              hipStream_t stream) {
    (void)in_sizes; (void)n_in; (void)out_size; (void)ws_size;
    const float* x  = (const float*)d_in[0];
    const int*   ei = (const int*)d_in[1];
    const int*   bt = (const int*)d_in[2];
    const float* W1 = (const float*)d_in[3];
    const float* b1 = (const float*)d_in[4];
    const float* W2 = (const float*)d_in[5];
    const float* b2 = (const float*)d_in[6];
    const float* W3 = (const float*)d_in[7];
    const float* b3 = (const float*)d_in[8];
    float* out = (float*)d_out;
    char* ws = (char*)d_ws;

    size_t o = 0;
    auto alloc = [&](size_t bytes) { size_t r = o; o = (o + bytes + 511) & ~(size_t)511; return r; };
    // zeroed region: deg + fill (one memset)
    int*    deg  = (int*)(ws + alloc((size_t)NN * 4));
    int*    fill = (int*)(ws + alloc((size_t)NN * 4));
    size_t zbytes = o;
    float*  dinv = (float*)(ws + alloc((size_t)NN * 4));
    int*    rp   = (int*)(ws + alloc((size_t)(NN + 1) * 4));
    int*    bs   = (int*)(ws + alloc(256 * 4));
    int*    col  = (int*)(ws + alloc((size_t)(NE + NN) * 4));
    short*  wpk  = (short*)(ws + alloc((size_t)3 * 32768 * 2));
    ushort* hsT  = (ushort*)(ws + alloc((size_t)NN * DD * 2));
    ushort* hsA  = (ushort*)(ws + alloc((size_t)NN * DD * 2));
    float*  F    = (float*)(ws + alloc((size_t)NN * DD * 4));

    const int* srcv = ei;        // edge_index[0]
    const int* dstv = ei + NE;   // edge_index[1]

    hipMemsetAsync(ws, 0, zbytes, stream);

    k_hist<<<(NE + 255) / 256, 256, 0, stream>>>(dstv, deg);
    k_scan1<<<196, 256, 0, stream>>>(deg, dinv, rp, bs);
    k_scan23<<<196, 256, 0, stream>>>(rp, bs);
    k_scatter<<<(NE + NN + 255) / 256, 256, 0, stream>>>(srcv, dstv, rp, fill, col);
    k_wpack<<<dim3(8, 3), 256, 0, stream>>>(W1, W2, W3, wpk);

    const dim3 gG((NN + 127) / 128, 2);   // 391 x 2
    k_gemm_mfma<1><<<gG, 256, 0, stream>>>(x, wpk, dinv, hsT);
    k_agg<1, 0><<<12500, 256, 0, stream>>>(hsT, col, rp, dinv, b1, hsA);
    k_gemm_mfma<0><<<gG, 256, 0, stream>>>(hsA, wpk + 32768, dinv, hsT);
    k_agg<1, 0><<<12500, 256, 0, stream>>>(hsT, col, rp, dinv, b2, hsA);
    k_gemm_mfma<0><<<gG, 256, 0, stream>>>(hsA, wpk + 65536, dinv, hsT);
    k_agg<0, 1><<<12500, 256, 0, stream>>>(hsT, col, rp, dinv, b3, F);

    k_poolfinal<<<NG, 128, 0, stream>>>(F, bt, out);
}

// Round 6
// 317.214 us; speedup vs baseline: 1.4237x; 1.1018x over previous
//
#include <hip/hip_runtime.h>

#define NN 50000
#define NE 600000
#define DD 128
#define NG 64

typedef unsigned int uint;
typedef unsigned short ushort;
typedef __attribute__((ext_vector_type(8))) short short8;
typedef __attribute__((ext_vector_type(4))) float f4;

// ---------------- bf16 helpers ----------------

__device__ __forceinline__ float bf_lo(uint v) { return __uint_as_float(v << 16); }
__device__ __forceinline__ float bf_hi(uint v) { return __uint_as_float(v & 0xffff0000u); }
__device__ __forceinline__ float bf2f(ushort h) { return __uint_as_float((uint)h << 16); }
__device__ __forceinline__ ushort f2bf(float f) {
    uint u = __float_as_uint(f);
    uint r = (u + 0x7fffu + ((u >> 16) & 1u)) >> 16;   // round-nearest-even
    return (ushort)r;
}

// ---------------- setup kernels ----------------

__global__ void k_hist(const int* __restrict__ dstv, int* __restrict__ deg) {
    int e = blockIdx.x * 256 + threadIdx.x;
    if (e < NE) atomicAdd(&deg[dstv[e]], 1);
}

// deg holds edge-count only; +1 self-loop folded in here.
__global__ void k_scan1(const int* __restrict__ deg, float* __restrict__ dinv,
                        int* __restrict__ rp, int* __restrict__ bsum) {
    __shared__ int s[256];
    int t = threadIdx.x, i = blockIdx.x * 256 + t;
    int v = (i < NN) ? (deg[i] + 1) : 0;
    if (i < NN) dinv[i] = rsqrtf((float)v);
    s[t] = v; __syncthreads();
    for (int off = 1; off < 256; off <<= 1) {
        int x = (t >= off) ? s[t - off] : 0;
        __syncthreads();
        s[t] += x;
        __syncthreads();
    }
    if (i < NN) rp[i] = s[t] - v;           // exclusive
    if (t == 255) bsum[blockIdx.x] = s[255];
}

// fused scan2+scan3: every block scans the 196 block-sums itself, adds prefix.
__global__ void k_scan23(int* __restrict__ rp, const int* __restrict__ bs) {
    __shared__ int s[256];
    int t = threadIdx.x;
    int v = (t < 196) ? bs[t] : 0;
    s[t] = v; __syncthreads();
    for (int off = 1; off < 256; off <<= 1) {
        int x = (t >= off) ? s[t - off] : 0;
        __syncthreads();
        s[t] += x;
        __syncthreads();
    }
    __shared__ int ps[256];
    ps[t] = s[t] - v;                        // exclusive
    __syncthreads();
    int add = ps[blockIdx.x];
    int i = blockIdx.x * 256 + t;
    if (i < NN) rp[i] += add;
    if (i == 0) rp[NN] = NE + NN;
}

__global__ void k_scatter(const int* __restrict__ srcv, const int* __restrict__ dstv,
                          const int* __restrict__ rp, int* __restrict__ fill,
                          int* __restrict__ col) {
    int t = blockIdx.x * 256 + threadIdx.x;
    if (t < NE) {
        int s = srcv[t], d = dstv[t];
        int pos = rp[d] + atomicAdd(&fill[d], 1);
        col[pos] = s;
    } else if (t < NE + NN) {
        int i = t - NE;
        int pos = rp[i] + atomicAdd(&fill[i], 1);
        col[pos] = i;
    }
}

// Pack W [128x128 f32] into MFMA B-fragment layout, split bf16 hi + lo.
__global__ void k_wpack(const float* __restrict__ W1, const float* __restrict__ W2,
                        const float* __restrict__ W3, short* __restrict__ out) {
    const float* W = (blockIdx.y == 0) ? W1 : (blockIdx.y == 1) ? W2 : W3;
    short* base = out + (size_t)blockIdx.y * 32768;
    int g = blockIdx.x * 256 + threadIdx.x;   // 0..2047
    int nt = g >> 8, kk = (g >> 6) & 3, lane = g & 63;
    int k0 = kk * 32 + (lane >> 4) * 8;
    int n = nt * 16 + (lane & 15);
    #pragma unroll
    for (int j = 0; j < 8; ++j) {
        float w = W[(size_t)(k0 + j) * DD + n];
        ushort h = f2bf(w);
        float r = w - bf2f(h);
        base[g * 8 + j] = (short)h;
        base[16384 + g * 8 + j] = (short)f2bf(r);
    }
}

// ---------------- MFMA GEMM ----------------
// out[r][c] = bf16( (X[r][:] @ W[:][c]) * dinv[r] )
// N split across blockIdx.y (2 halves of 64 cols); 32 KB LDS for W frags,
// reused post-barrier to stage C for coalesced float4 stores.
#define CST 72   // C-stage LDS row stride in shorts
template <int INF32>
__global__ __launch_bounds__(256) void k_gemm_mfma(const void* __restrict__ Xv,
                                                   const short* __restrict__ wpk,
                                                   const float* __restrict__ dinv,
                                                   ushort* __restrict__ out) {
    __shared__ short lds[16384];   // W: hi [0,8192), lo [8192,16384); C-stage reuse
    const int t = threadIdx.x;
    const int yb = blockIdx.y * 8192;
    #pragma unroll
    for (int m = 0; m < 4; ++m) {
        int idx = (m * 256 + t) * 8;
        *(float4*)&lds[idx] = *(const float4*)&wpk[yb + idx];
        *(float4*)&lds[8192 + idx] = *(const float4*)&wpk[16384 + yb + idx];
    }

    const int wv = t >> 6, lane = t & 63;
    const int quad = lane >> 4, l16 = lane & 15;
    const int r0 = blockIdx.x * 128 + wv * 32;

    short8 aH[2][4], aL[2][4];
    #pragma unroll
    for (int s = 0; s < 2; ++s) {
        int row = r0 + s * 16 + l16;
        #pragma unroll
        for (int kk = 0; kk < 4; ++kk) {
            int koff = kk * 32 + quad * 8;
            if (INF32) {
                float4 x0 = make_float4(0.f, 0.f, 0.f, 0.f), x1 = x0;
                if (row < NN) {
                    const float* p = (const float*)Xv + (size_t)row * DD + koff;
                    x0 = *(const float4*)p; x1 = *(const float4*)(p + 4);
                }
                float xs[8] = {x0.x, x0.y, x0.z, x0.w, x1.x, x1.y, x1.z, x1.w};
                short8 h, l;
                #pragma unroll
                for (int j = 0; j < 8; ++j) {
                    ushort hb = f2bf(xs[j]);
                    h[j] = (short)hb;
                    l[j] = (short)f2bf(xs[j] - bf2f(hb));
                }
                aH[s][kk] = h; aL[s][kk] = l;
            } else {
                short8 h = {0, 0, 0, 0, 0, 0, 0, 0};
                if (row < NN)
                    h = *(const short8*)((const ushort*)Xv + (size_t)row * DD + koff);
                aH[s][kk] = h;
            }
        }
    }
    __syncthreads();

    float dv[2][4];
    #pragma unroll
    for (int s = 0; s < 2; ++s)
        #pragma unroll
        for (int i = 0; i < 4; ++i) {
            int row = r0 + s * 16 + quad * 4 + i;
            dv[s][i] = (row < NN) ? dinv[row] : 0.f;
        }

    f4 acc[2][4];
    #pragma unroll
    for (int s = 0; s < 2; ++s)
        #pragma unroll
        for (int nt = 0; nt < 4; ++nt)
            acc[s][nt] = (f4){0.f, 0.f, 0.f, 0.f};

    #pragma unroll
    for (int nt = 0; nt < 4; ++nt) {
        #pragma unroll
        for (int kk = 0; kk < 4; ++kk) {
            int fi = ((nt * 4 + kk) * 64 + lane) * 8;
            short8 bh = *(const short8*)&lds[fi];
            short8 bl = *(const short8*)&lds[8192 + fi];
            acc[0][nt] = __builtin_amdgcn_mfma_f32_16x16x32_bf16(aH[0][kk], bh, acc[0][nt], 0, 0, 0);
            acc[0][nt] = __builtin_amdgcn_mfma_f32_16x16x32_bf16(aH[0][kk], bl, acc[0][nt], 0, 0, 0);
            acc[1][nt] = __builtin_amdgcn_mfma_f32_16x16x32_bf16(aH[1][kk], bh, acc[1][nt], 0, 0, 0);
            acc[1][nt] = __builtin_amdgcn_mfma_f32_16x16x32_bf16(aH[1][kk], bl, acc[1][nt], 0, 0, 0);
            if (INF32) {
                acc[0][nt] = __builtin_amdgcn_mfma_f32_16x16x32_bf16(aL[0][kk], bh, acc[0][nt], 0, 0, 0);
                acc[1][nt] = __builtin_amdgcn_mfma_f32_16x16x32_bf16(aL[1][kk], bh, acc[1][nt], 0, 0, 0);
            }
        }
    }

    __syncthreads();   // reuse LDS for C stage
    #pragma unroll
    for (int s = 0; s < 2; ++s) {
        int lr = wv * 32 + s * 16 + quad * 4;
        #pragma unroll
        for (int nt = 0; nt < 4; ++nt)
            #pragma unroll
            for (int i = 0; i < 4; ++i)
                lds[(lr + i) * CST + nt * 16 + l16] = (short)f2bf(acc[s][nt][i] * dv[s][i]);
    }
    __syncthreads();

    int row = t >> 1, half = t & 1;
    int grow = blockIdx.x * 128 + row;
    if (grow < NN) {
        #pragma unroll
        for (int j = 0; j < 4; ++j) {
            float4 v = *(float4*)&lds[row * CST + half * 32 + j * 8];
            *(float4*)&out[(size_t)grow * DD + blockIdx.y * 64 + half * 32 + j * 8] = v;
        }
    }
}

// ---------------- aggregation ----------------
// out[i] = maybe_relu( dinv[i] * sum_{p in row i} hs[col[p]] + bias )
// Wave per node, lane = 1 dword (2 dims); 8 gather rows in flight.
template <int RELU, int OUTF32>
__global__ __launch_bounds__(256) void k_agg(const ushort* __restrict__ hs,
                                             const int* __restrict__ col,
                                             const int* __restrict__ rp,
                                             const float* __restrict__ dinv,
                                             const float* __restrict__ bias,
                                             void* __restrict__ outv) {
    int w = threadIdx.x >> 6, lane = threadIdx.x & 63;
    int i = blockIdx.x * 4 + w;
    if (i >= NN) return;
    int p0 = rp[i], p1 = rp[i + 1];
    int d = lane * 2;
    const ushort* hsd = hs + d;
    float x0 = 0.f, y0 = 0.f, x1 = 0.f, y1 = 0.f;
    float x2 = 0.f, y2 = 0.f, x3 = 0.f, y3 = 0.f;
    int p = p0;
    for (; p + 8 <= p1; p += 8) {
        int c0 = col[p],     c1 = col[p + 1], c2 = col[p + 2], c3 = col[p + 3];
        int c4 = col[p + 4], c5 = col[p + 5], c6 = col[p + 6], c7 = col[p + 7];
        uint v0 = *(const uint*)(hsd + (size_t)c0 * DD);
        uint v1 = *(const uint*)(hsd + (size_t)c1 * DD);
        uint v2 = *(const uint*)(hsd + (size_t)c2 * DD);
        uint v3 = *(const uint*)(hsd + (size_t)c3 * DD);
        uint v4 = *(const uint*)(hsd + (size_t)c4 * DD);
        uint v5 = *(const uint*)(hsd + (size_t)c5 * DD);
        uint v6 = *(const uint*)(hsd + (size_t)c6 * DD);
        uint v7 = *(const uint*)(hsd + (size_t)c7 * DD);
        x0 += bf_lo(v0); y0 += bf_hi(v0); x1 += bf_lo(v1); y1 += bf_hi(v1);
        x2 += bf_lo(v2); y2 += bf_hi(v2); x3 += bf_lo(v3); y3 += bf_hi(v3);
        x0 += bf_lo(v4); y0 += bf_hi(v4); x1 += bf_lo(v5); y1 += bf_hi(v5);
        x2 += bf_lo(v6); y2 += bf_hi(v6); x3 += bf_lo(v7); y3 += bf_hi(v7);
    }
    for (; p + 2 <= p1; p += 2) {
        int c0 = col[p], c1 = col[p + 1];
        uint v0 = *(const uint*)(hsd + (size_t)c0 * DD);
        uint v1 = *(const uint*)(hsd + (size_t)c1 * DD);
        x0 += bf_lo(v0); y0 += bf_hi(v0); x1 += bf_lo(v1); y1 += bf_hi(v1);
    }
    if (p < p1) {
        uint v = *(const uint*)(hsd + (size_t)col[p] * DD);
        x0 += bf_lo(v); y0 += bf_hi(v);
    }
    float ax = (x0 + x1) + (x2 + x3);
    float ay = (y0 + y1) + (y2 + y3);
    float s = dinv[i];
    float2 bb = *(const float2*)(bias + d);
    float ox = fmaf(s, ax, bb.x), oy = fmaf(s, ay, bb.y);
    if (RELU) { ox = fmaxf(ox, 0.f); oy = fmaxf(oy, 0.f); }
    if (OUTF32) {
        *(float2*)((float*)outv + (size_t)i * DD + d) = make_float2(ox, oy);
    } else {
        ushort2 o; o.x = f2bf(ox); o.y = f2bf(oy);
        *(ushort2*)((ushort*)outv + (size_t)i * DD + d) = o;
    }
}

// ---------------- pool ----------------
// batch sorted: 391 blocks x 128 dims, run-length accumulate per 128-node
// chunk, one atomicAdd per (graph transition, dim). ~58k atomics total.
__global__ __launch_bounds__(128) void k_pool(const float* __restrict__ h,
                                              const int* __restrict__ batch,
                                              float* __restrict__ sums,
                                              float* __restrict__ cnt) {
    int d = threadIdx.x;  // 0..127
    int start = blockIdx.x * 128;
    if (start >= NN) return;
    int end = min(start + 128, NN);
    float acc = 0.f, c = 0.f;
    int g = batch[start];
    for (int i = start; i < end; ++i) {
        int gi = batch[i];
        if (gi != g) {
            atomicAdd(&sums[g * DD + d], acc);
            if (d == 0) atomicAdd(&cnt[g], c);
            acc = 0.f; c = 0.f; g = gi;
        }
        acc += h[(size_t)i * DD + d];
        c += 1.f;
    }
    atomicAdd(&sums[g * DD + d], acc);
    if (d == 0) atomicAdd(&cnt[g], c);
}

__global__ void k_final(const float* __restrict__ sums, const float* __restrict__ cnt,
                        float* __restrict__ out) {
    int i = blockIdx.x * 256 + threadIdx.x;  // < NG*DD = 8192
    int g = i >> 7;
    out[i] = sums[i] / fmaxf(cnt[g], 1.f);
}

// ---------------- launch ----------------

extern "C" void kernel_launch(void* const* d_in, const int* in_sizes, int n_in,
                              void* d_out, int out_size, void* d_ws, size_t ws_size,
                              hipStream_t stream) {
    (void)in_sizes; (void)n_in; (void)out_size; (void)ws_size;
    const float* x  = (const float*)d_in[0];
    const int*   ei = (const int*)d_in[1];
    const int*   bt = (const int*)d_in[2];
    const float* W1 = (const float*)d_in[3];
    const float* b1 = (const float*)d_in[4];
    const float* W2 = (const float*)d_in[5];
    const float* b2 = (const float*)d_in[6];
    const float* W3 = (const float*)d_in[7];
    const float* b3 = (const float*)d_in[8];
    float* out = (float*)d_out;
    char* ws = (char*)d_ws;

    size_t o = 0;
    auto alloc = [&](size_t bytes) { size_t r = o; o = (o + bytes + 511) & ~(size_t)511; return r; };
    // zeroed region: deg + fill + pool + cnt (one memset)
    int*    deg  = (int*)(ws + alloc((size_t)NN * 4));
    int*    fill = (int*)(ws + alloc((size_t)NN * 4));
    float*  pool = (float*)(ws + alloc((size_t)(NG * DD + NG) * 4));
    float*  cnt  = pool + NG * DD;
    size_t zbytes = o;
    float*  dinv = (float*)(ws + alloc((size_t)NN * 4));
    int*    rp   = (int*)(ws + alloc((size_t)(NN + 1) * 4));
    int*    bs   = (int*)(ws + alloc(256 * 4));
    int*    col  = (int*)(ws + alloc((size_t)(NE + NN) * 4));
    short*  wpk  = (short*)(ws + alloc((size_t)3 * 32768 * 2));
    ushort* hsT  = (ushort*)(ws + alloc((size_t)NN * DD * 2));
    ushort* hsA  = (ushort*)(ws + alloc((size_t)NN * DD * 2));
    float*  F    = (float*)(ws + alloc((size_t)NN * DD * 4));

    const int* srcv = ei;        // edge_index[0]
    const int* dstv = ei + NE;   // edge_index[1]

    hipMemsetAsync(ws, 0, zbytes, stream);

    k_hist<<<(NE + 255) / 256, 256, 0, stream>>>(dstv, deg);
    k_scan1<<<196, 256, 0, stream>>>(deg, dinv, rp, bs);
    k_scan23<<<196, 256, 0, stream>>>(rp, bs);
    k_scatter<<<(NE + NN + 255) / 256, 256, 0, stream>>>(srcv, dstv, rp, fill, col);
    k_wpack<<<dim3(8, 3), 256, 0, stream>>>(W1, W2, W3, wpk);

    const dim3 gG((NN + 127) / 128, 2);   // 391 x 2
    k_gemm_mfma<1><<<gG, 256, 0, stream>>>(x, wpk, dinv, hsT);
    k_agg<1, 0><<<12500, 256, 0, stream>>>(hsT, col, rp, dinv, b1, hsA);
    k_gemm_mfma<0><<<gG, 256, 0, stream>>>(hsA, wpk + 32768, dinv, hsT);
    k_agg<1, 0><<<12500, 256, 0, stream>>>(hsT, col, rp, dinv, b2, hsA);
    k_gemm_mfma<0><<<gG, 256, 0, stream>>>(hsA, wpk + 65536, dinv, hsT);
    k_agg<0, 1><<<12500, 256, 0, stream>>>(hsT, col, rp, dinv, b3, F);

    k_pool<<<(NN + 127) / 128, 128, 0, stream>>>(F, bt, pool, cnt);
    k_final<<<(NG * DD) / 256, 256, 0, stream>>>(pool, cnt, out);
}